// Round 2
// baseline (250.169 us; speedup 1.0000x reference)
//
#include <hip/hip_runtime.h>
#include <stdint.h>

#define DEV static __device__ __forceinline__

typedef __attribute__((ext_vector_type(4)))  float f32x4;
typedef __attribute__((ext_vector_type(16))) float f32x16;
typedef __bf16 bf16x8 __attribute__((ext_vector_type(8)));

// ---------------- problem constants ----------------
constexpr int Bc = 2, S = 2048, Dm = 1024, H = 16, DH = 64;
constexpr int BS  = Bc * S;                 // 4096 rows
constexpr int HSZ = Bc * H * S * DH;        // 4,194,304 elems per head tensor

// ws layout (byte offsets)
constexpr size_t OFF_QKVB  = 0;              // [3][4096][1024] bf16   25,165,824
constexpr size_t OFF_WT    = 25165824;       // [4][1024][1024] bf16    8,388,608
constexpr size_t OFF_HEADS = 33554432;       // [3][2][16][2048][64]   25,165,824
constexpr size_t OFF_VT    = 58720256;       // [2][16][64][2048]       8,388,608
constexpr size_t OFF_O     = 67108864;       // [4096][1024] bf16       8,388,608
// total 75,497,472 bytes

// ---------------- helpers ----------------
DEV uint16_t f2bf(float f) {                  // fp32 -> bf16 RNE
    uint32_t u = __float_as_uint(f);
    uint32_t r = u + 0x7FFFu + ((u >> 16) & 1u);
    return (uint16_t)(r >> 16);
}
DEV uint32_t pk2bf(float lo, float hi) {
    return (uint32_t)f2bf(lo) | ((uint32_t)f2bf(hi) << 16);
}
// XOR swizzle for LDS tiles with 128-byte rows: 16B-chunk ^= (row & 7).
// Involution; preserves 16B alignment; permutes chunks only within a row.
DEV uint32_t swz128(uint32_t byteoff) {
    return byteoff ^ (((byteoff >> 7) & 7u) << 4);
}
DEV void gll16(const void* g, void* l) {      // async global -> LDS, 16B per lane
    auto gp = (const __attribute__((address_space(1))) uint32_t*)g;
    auto lp = (__attribute__((address_space(3))) uint32_t*)l;
    __builtin_amdgcn_global_load_lds(gp, lp, 16, 0, 0);
}
DEV bf16x8 ld_frag(const char* base, uint32_t logical_off) {  // swizzled LDS read
    return __builtin_bit_cast(bf16x8, *(const uint4*)(base + swz128(logical_off)));
}
DEV bf16x8 ld_frag_g(const void* p) {         // 16B global read
    return __builtin_bit_cast(bf16x8, *(const uint4*)p);
}

// ---------------- kernel 1: convert q,k,v fp32 -> bf16 [3][4096][1024] ----------------
__global__ __launch_bounds__(256) void k_convert(const float* __restrict__ q,
                                                 const float* __restrict__ k,
                                                 const float* __restrict__ v,
                                                 uint16_t* __restrict__ out) {
    const int64_t n1 = (int64_t)BS * Dm;
    int64_t i = ((int64_t)blockIdx.x * 256 + threadIdx.x) * 8;
    const float* src; int64_t j;
    if (i < n1)            { src = q; j = i; }
    else if (i < 2 * n1)   { src = k; j = i - n1; }
    else                   { src = v; j = i - 2 * n1; }
    float4 a = *(const float4*)(src + j);
    float4 b = *(const float4*)(src + j + 4);
    union { uint16_t u[8]; uint4 q4; } o;
    o.u[0] = f2bf(a.x); o.u[1] = f2bf(a.y); o.u[2] = f2bf(a.z); o.u[3] = f2bf(a.w);
    o.u[4] = f2bf(b.x); o.u[5] = f2bf(b.y); o.u[6] = f2bf(b.z); o.u[7] = f2bf(b.w);
    *(uint4*)(out + i) = o.q4;
}

// ---------------- kernel 2: W^T bf16 (scale folded into Wq) ----------------
__global__ __launch_bounds__(256) void k_transw(const float* __restrict__ w0,
                                                const float* __restrict__ w1,
                                                const float* __restrict__ w2,
                                                const float* __restrict__ w3,
                                                uint16_t* __restrict__ wt) {
    int mat = blockIdx.y;
    const float* w = (mat == 0) ? w0 : (mat == 1) ? w1 : (mat == 2) ? w2 : w3;
    float scale = (mat == 0) ? 0.125f : 1.0f;     // 1/sqrt(64) folded into Wq
    uint16_t* out = wt + (size_t)mat * 1024 * 1024;
    int tile = blockIdx.x;                        // 16x16 tiles of 64x64
    int tr = (tile >> 4) << 6, tc = (tile & 15) << 6;   // tr = k0, tc = n0
    __shared__ float lds[64][65];
    int t = threadIdx.x;
#pragma unroll
    for (int p = 0; p < 4; ++p) {
        int r = p * 16 + (t >> 4);
        int c = (t & 15) * 4;
        float4 x = *(const float4*)(w + (size_t)(tr + r) * 1024 + tc + c);
        lds[r][c] = x.x; lds[r][c + 1] = x.y; lds[r][c + 2] = x.z; lds[r][c + 3] = x.w;
    }
    __syncthreads();
    int n = t >> 2, kc = (t & 3) * 16;
    union { uint16_t u[16]; uint4 q[2]; } tt;
#pragma unroll
    for (int j = 0; j < 16; ++j) tt.u[j] = f2bf(lds[kc + j][n] * scale);
    uint16_t* dst = out + (size_t)(tc + n) * 1024 + tr + kc;   // WT[n][k] = W[k][n]*scale
    *(uint4*)dst = tt.q[0];
    *(uint4*)(dst + 8) = tt.q[1];
}

// ---------------- shared GEMM core: 128x128 tile, BK=64, 4 waves ----------------
// A [.][K] bf16 row-major (pre-offset to tile row 0), Bt [.][K] bf16 (pre-offset)
struct Acc { f32x4 a[4][4]; };

DEV void stage128(const uint16_t* g, int ldbytes, char* lds) {
    int tid = threadIdx.x;                        // 256 threads x 4 issues x 16B = 16KB
#pragma unroll
    for (int it = 0; it < 4; ++it) {
        uint32_t p = it * 4096 + tid * 16;        // physical LDS offset this lane fills
        uint32_t lo = swz128(p);                  // -> logical offset: pre-swizzled source
        uint32_t row = lo >> 7, col = lo & 127;
        gll16((const char*)g + (size_t)row * ldbytes + col,
              lds + it * 4096 + (tid & ~63) * 16);  // wave-uniform base + lane*16
    }
}

DEV void gemm_core(const uint16_t* A, const uint16_t* Bt, int K,
                   char* la, char* lb, Acc& acc) {
    int lane = threadIdx.x & 63, w = threadIdx.x >> 6;
    int wr = w >> 1, wc = w & 1;
#pragma unroll
    for (int mf = 0; mf < 4; ++mf)
#pragma unroll
        for (int nf = 0; nf < 4; ++nf)
#pragma unroll
            for (int r = 0; r < 4; ++r) acc.a[mf][nf][r] = 0.f;
    for (int k0 = 0; k0 < K; k0 += 64) {
        __syncthreads();                          // prev reads done -> LDS reusable
        stage128(A + k0, K * 2, la);
        stage128(Bt + k0, K * 2, lb);
        __syncthreads();                          // drains vmcnt -> staged data visible
#pragma unroll
        for (int kk = 0; kk < 2; ++kk) {
            bf16x8 af[4], bfr[4];
#pragma unroll
            for (int mf = 0; mf < 4; ++mf) {
                uint32_t row = wr * 64 + mf * 16 + (lane & 15);
                af[mf] = ld_frag(la, row * 128 + kk * 64 + (lane >> 4) * 16);
            }
#pragma unroll
            for (int nf = 0; nf < 4; ++nf) {
                uint32_t row = wc * 64 + nf * 16 + (lane & 15);
                bfr[nf] = ld_frag(lb, row * 128 + kk * 64 + (lane >> 4) * 16);
            }
#pragma unroll
            for (int mf = 0; mf < 4; ++mf)
#pragma unroll
                for (int nf = 0; nf < 4; ++nf)
                    acc.a[mf][nf] = __builtin_amdgcn_mfma_f32_16x16x32_bf16(
                        af[mf], bfr[nf], acc.a[mf][nf], 0, 0, 0);
        }
    }
}

// ---------------- kernel 3: fused QKV projection GEMM, head-split epilogue ----------------
__global__ __launch_bounds__(256) void k_proj(const uint16_t* __restrict__ qkvb,
                                              const uint16_t* __restrict__ WT,
                                              uint16_t* __restrict__ heads) {
    __shared__ char lds[32768];
    int blk = blockIdx.x;                     // 768 = 3 * (32 m-tiles * 8 n-tiles)
    int sel = blk >> 8;
    int t2 = blk & 255; int bm = t2 >> 3, bn = t2 & 7;
    const uint16_t* A  = qkvb + (size_t)sel * BS * Dm + (size_t)bm * 128 * Dm;
    const uint16_t* Bt = WT   + (size_t)sel * Dm * Dm + (size_t)bn * 128 * Dm;
    Acc acc;
    gemm_core(A, Bt, 1024, lds, lds + 16384, acc);
    uint16_t* out = heads + (size_t)sel * HSZ;
    int lane = threadIdx.x & 63, w = threadIdx.x >> 6;
    int m_base = bm * 128 + (w >> 1) * 64, n_base = bn * 128 + (w & 1) * 64;
#pragma unroll
    for (int mf = 0; mf < 4; ++mf)
#pragma unroll
        for (int nf = 0; nf < 4; ++nf)
#pragma unroll
            for (int r = 0; r < 4; ++r) {
                int m = m_base + mf * 16 + (lane >> 4) * 4 + r;   // C row (verified layout)
                int n = n_base + nf * 16 + (lane & 15);           // C col
                int b = m >> 11, s = m & 2047, h = n >> 6, d = n & 63;
                out[(((size_t)(b * H + h)) * S + s) * 64 + d] = f2bf(acc.a[mf][nf][r]);
            }
}

// ---------------- kernel 4: Vh [bh][s][64] -> Vt [bh][64][s] ----------------
__global__ __launch_bounds__(256) void k_transv(const uint16_t* __restrict__ Vh,
                                                uint16_t* __restrict__ Vt) {
    int bh = blockIdx.x >> 5, st = blockIdx.x & 31;
    int s0 = st * 64;
    const uint16_t* src = Vh + (size_t)bh * S * 64 + (size_t)s0 * 64;
    uint16_t* dst = Vt + (size_t)bh * 64 * S;
    __shared__ uint16_t lds[64][65];
    int t = threadIdx.x;
    {
        int r = t >> 2, c = (t & 3) * 16;
        union { uint16_t u[16]; uint4 q[2]; } x;
        x.q[0] = *(const uint4*)(src + (size_t)r * 64 + c);
        x.q[1] = *(const uint4*)(src + (size_t)r * 64 + c + 8);
#pragma unroll
        for (int j = 0; j < 16; ++j) lds[r][c + j] = x.u[j];
    }
    __syncthreads();
    {
        int d = t >> 2, sc = (t & 3) * 16;
        union { uint16_t u[16]; uint4 q[2]; } x;
#pragma unroll
        for (int j = 0; j < 16; ++j) x.u[j] = lds[sc + j][d];
        uint16_t* p = dst + (size_t)d * S + s0 + sc;
        *(uint4*)p = x.q[0];
        *(uint4*)(p + 8) = x.q[1];
    }
}

// ---------------- kernel 5: fused ReLU15 attention ----------------
// grid: 256 blocks = 32 heads * 8 q-blocks of 256 rows; 512 threads = 8 waves * 32 q-rows.
// No softmax state: per KV tile it is GEMM -> clip -> GEMM. S^T via swapped
// mfma(A=K,B=Q) so each lane owns P[kv...][q=lane&31]; permlane32_swap repacks
// C-frags into PV A-frags entirely in-register (no P LDS round trip).
__global__ __launch_bounds__(512) void k_attn(const uint16_t* __restrict__ Qh,
                                              const uint16_t* __restrict__ Kh,
                                              const uint16_t* __restrict__ Vt,
                                              uint16_t* __restrict__ O) {
    __shared__ char kbuf[2][8192];
    __shared__ char vbuf[2][8192];
    int bh = blockIdx.x >> 3, qb = (blockIdx.x & 7) * 256;
    int tid = threadIdx.x, lane = tid & 63, w = tid >> 6;
    int l31 = lane & 31, hi = lane >> 5;
    const char* Kbase = (const char*)(Kh + (size_t)bh * S * 64);
    const char* Vbase = (const char*)(Vt + (size_t)bh * 64 * S);

    // Q fragments in registers (1/TEMP pre-folded into Wq): B-operand, col = q = l31
    bf16x8 qf[4];
    {
        const char* qrow = (const char*)(Qh + (size_t)bh * S * 64
                                         + (size_t)(qb + w * 32 + l31) * 64);
#pragma unroll
        for (int ks = 0; ks < 4; ++ks)
            qf[ks] = ld_frag_g(qrow + ks * 32 + hi * 16);
    }
    f32x16 oa[2];
#pragma unroll
    for (int nt = 0; nt < 2; ++nt)
#pragma unroll
        for (int r = 0; r < 16; ++r) oa[nt][r] = 0.f;

    // staging: both tiles are [64 rows][128B]; pre-swizzled global source
    auto stageKV = [&](int tile, int bufi) {
        int kv0 = tile * 64;
        uint32_t p = tid * 16;                   // physical LDS offset (512 thr = 8KB)
        uint32_t lo = swz128(p);
        uint32_t row = lo >> 7, col = lo & 127;
        gll16(Kbase + (size_t)(kv0 + row) * 128 + col, kbuf[bufi] + (tid & ~63) * 16);
        gll16(Vbase + (size_t)row * 4096 + (size_t)kv0 * 2 + col, vbuf[bufi] + (tid & ~63) * 16);
    };

    stageKV(0, 0);
    __syncthreads();
    for (int t = 0; t < 32; ++t) {
        int cur = t & 1;
        if (t < 31) stageKV(t + 1, cur ^ 1);     // in flight across the compute phase
        __builtin_amdgcn_s_setprio(1);
#pragma unroll
        for (int mt = 0; mt < 2; ++mt) {
            // S^T = mfma(A=K, B=Q): C col = q = l31 (m74/m101-verified layout)
            f32x16 c;
#pragma unroll
            for (int r = 0; r < 16; ++r) c[r] = 0.f;
#pragma unroll
            for (int ks = 0; ks < 4; ++ks) {
                uint32_t row = mt * 32 + l31;
                bf16x8 a = ld_frag(kbuf[cur], row * 128 + ks * 32 + hi * 16);
                c = __builtin_amdgcn_mfma_f32_32x32x16_bf16(a, qf[ks], c, 0, 0, 0);
            }
#pragma unroll
            for (int r = 0; r < 16; ++r) c[r] = fminf(fmaxf(c[r], 0.f), 15.f);
            // repack P^T C-frags -> PV A-frags:
            //   lane holds kv=(r&3)+8*(r>>2)+4*hi; A-frag needs kv=ks2*16+hi*8+j.
            //   swap(pk(c[8k+2j],c[8k+2j+1]), pk(c[8k+4+2j],c[8k+4+2j+1])) fills
            //   words j and 2+j for both lane halves (verified by enumeration).
#pragma unroll
            for (int ks2 = 0; ks2 < 2; ++ks2) {
                uint32_t wds[4];
#pragma unroll
                for (int jj = 0; jj < 2; ++jj) {
                    uint32_t sA = pk2bf(c[8 * ks2 + 2 * jj],     c[8 * ks2 + 2 * jj + 1]);
                    uint32_t sB = pk2bf(c[8 * ks2 + 4 + 2 * jj], c[8 * ks2 + 4 + 2 * jj + 1]);
                    asm volatile("v_permlane32_swap_b32 %0, %1" : "+v"(sA), "+v"(sB));
                    wds[jj] = sA; wds[2 + jj] = sB;
                }
                union { uint32_t w[4]; bf16x8 v; } pa;
                pa.w[0] = wds[0]; pa.w[1] = wds[1]; pa.w[2] = wds[2]; pa.w[3] = wds[3];
#pragma unroll
                for (int nt = 0; nt < 2; ++nt) {
                    uint32_t row = nt * 32 + l31;                         // dv row of V^T
                    uint32_t kcol = mt * 64 + ks2 * 32 + hi * 16;         // kv bytes
                    bf16x8 vb = ld_frag(vbuf[cur], row * 128 + kcol);
                    oa[nt] = __builtin_amdgcn_mfma_f32_32x32x16_bf16(pa.v, vb, oa[nt], 0, 0, 0);
                }
            }
        }
        __builtin_amdgcn_s_setprio(0);
        __syncthreads();   // all waves done reading cur; t+1 stage drained & visible
    }
    int b = bh >> 4, h = bh & 15;
#pragma unroll
    for (int nt = 0; nt < 2; ++nt)
#pragma unroll
        for (int r = 0; r < 16; ++r) {
            int qg = qb + w * 32 + (r & 3) + 8 * (r >> 2) + 4 * hi;   // C row = q
            int col = h * 64 + nt * 32 + l31;                          // C col = dv
            O[((size_t)(b * S + qg)) * 1024 + col] = f2bf(oa[nt][r]);
        }
}

// ---------------- kernel 6: FC GEMM + residual -> d_out fp32 ----------------
__global__ __launch_bounds__(256) void k_fc(const uint16_t* __restrict__ Ob,
                                            const uint16_t* __restrict__ WfcT,
                                            const float* __restrict__ resid,
                                            float* __restrict__ out) {
    __shared__ char lds[32768];
    int blk = blockIdx.x;                     // 256 = 32 * 8
    int bm = blk >> 3, bn = blk & 7;
    const uint16_t* A  = Ob   + (size_t)bm * 128 * Dm;
    const uint16_t* Bt = WfcT + (size_t)bn * 128 * Dm;
    Acc acc;
    gemm_core(A, Bt, 1024, lds, lds + 16384, acc);
    int lane = threadIdx.x & 63, w = threadIdx.x >> 6;
    int m_base = bm * 128 + (w >> 1) * 64, n_base = bn * 128 + (w & 1) * 64;
#pragma unroll
    for (int mf = 0; mf < 4; ++mf)
#pragma unroll
        for (int nf = 0; nf < 4; ++nf)
#pragma unroll
            for (int r = 0; r < 4; ++r) {
                int m = m_base + mf * 16 + (lane >> 4) * 4 + r;
                int n = n_base + nf * 16 + (lane & 15);
                size_t idx = (size_t)m * 1024 + n;
                out[idx] = acc.a[mf][nf][r] + resid[idx];
            }
}

// ---------------- kernel 7: LayerNorm in-place on d_out ----------------
__global__ __launch_bounds__(256) void k_ln(float* __restrict__ io,
                                            const float* __restrict__ gamma,
                                            const float* __restrict__ beta) {
    int row = blockIdx.x;
    float* p = io + (size_t)row * 1024;
    int t = threadIdx.x;
    float4 x = *(const float4*)(p + t * 4);
    float s  = x.x + x.y + x.z + x.w;
    float s2 = x.x * x.x + x.y * x.y + x.z * x.z + x.w * x.w;
#pragma unroll
    for (int o = 32; o > 0; o >>= 1) { s += __shfl_xor(s, o); s2 += __shfl_xor(s2, o); }
    __shared__ float red[8];
    int w = t >> 6, lane = t & 63;
    if (lane == 0) { red[w] = s; red[4 + w] = s2; }
    __syncthreads();
    s  = red[0] + red[1] + red[2] + red[3];
    s2 = red[4] + red[5] + red[6] + red[7];
    float mu  = s * (1.f / 1024.f);
    float var = s2 * (1.f / 1024.f) - mu * mu;
    float inv = rsqrtf(var + 1e-6f);
    float4 g  = *(const float4*)(gamma + t * 4);
    float4 bb = *(const float4*)(beta + t * 4);
    x.x = (x.x - mu) * inv * g.x + bb.x;
    x.y = (x.y - mu) * inv * g.y + bb.y;
    x.z = (x.z - mu) * inv * g.z + bb.z;
    x.w = (x.w - mu) * inv * g.w + bb.w;
    *(float4*)(p + t * 4) = x;
}

// ---------------- launcher ----------------
extern "C" void kernel_launch(void* const* d_in, const int* in_sizes, int n_in,
                              void* d_out, int out_size, void* d_ws, size_t ws_size,
                              hipStream_t stream) {
    (void)in_sizes; (void)n_in; (void)out_size; (void)ws_size;
    const float* q     = (const float*)d_in[0];
    const float* k     = (const float*)d_in[1];
    const float* v     = (const float*)d_in[2];
    const float* Wq    = (const float*)d_in[3];
    const float* Wk    = (const float*)d_in[4];
    const float* Wv    = (const float*)d_in[5];
    const float* Wfc   = (const float*)d_in[6];
    const float* gamma = (const float*)d_in[7];
    const float* beta  = (const float*)d_in[8];
    char* ws = (char*)d_ws;
    uint16_t* qkvb  = (uint16_t*)(ws + OFF_QKVB);
    uint16_t* WT    = (uint16_t*)(ws + OFF_WT);
    uint16_t* heads = (uint16_t*)(ws + OFF_HEADS);
    uint16_t* Vt    = (uint16_t*)(ws + OFF_VT);
    uint16_t* Ob    = (uint16_t*)(ws + OFF_O);
    float* out = (float*)d_out;

    k_convert<<<dim3(6144), dim3(256), 0, stream>>>(q, k, v, qkvb);
    k_transw <<<dim3(256, 4), dim3(256), 0, stream>>>(Wq, Wk, Wv, Wfc, WT);
    k_proj   <<<dim3(768), dim3(256), 0, stream>>>(qkvb, WT, heads);
    k_transv <<<dim3(1024), dim3(256), 0, stream>>>(heads + 2 * (size_t)HSZ, Vt);
    k_attn   <<<dim3(256), dim3(512), 0, stream>>>(heads, heads + HSZ, Vt, Ob);
    k_fc     <<<dim3(256), dim3(256), 0, stream>>>(Ob, WT + 3 * 1024 * 1024, q, out);
    k_ln     <<<dim3(4096), dim3(256), 0, stream>>>(out, gamma, beta);
}